// Round 1
// baseline (1037.483 us; speedup 1.0000x reference)
//
#include <hip/hip_runtime.h>
#include <hip/hip_bf16.h>
#include <stdint.h>

typedef __attribute__((ext_vector_type(8))) short short8;
typedef __attribute__((ext_vector_type(4))) float f32x4;

#define DEVI __device__ __forceinline__

DEVI unsigned short f2bf(float f) {
  union { float f; unsigned int u; } c; c.f = f;
  unsigned int u = c.u;
  u += 0x7fffu + ((u >> 16) & 1u);   // round-to-nearest-even
  return (unsigned short)(u >> 16);
}

DEVI void gl_lds16(const void* gsrc, void* lds) {
  __builtin_amdgcn_global_load_lds(
      (const __attribute__((address_space(1))) unsigned int*)gsrc,
      (__attribute__((address_space(3))) unsigned int*)lds, 16, 0, 0);
}

// ---------------- fp32 -> bf16 convert (vectorized) ----------------
__global__ void cvt_f32_bf16(const float* __restrict__ in,
                             unsigned short* __restrict__ out, int n4) {
  const int stride = gridDim.x * blockDim.x;
  for (int i = blockIdx.x * blockDim.x + threadIdx.x; i < n4; i += stride) {
    const float4 v = ((const float4*)in)[i];
    ushort4 o;
    o.x = f2bf(v.x); o.y = f2bf(v.y); o.z = f2bf(v.z); o.w = f2bf(v.w);
    ((ushort4*)out)[i] = o;
  }
}

// ---------------- bf16 GEMM:  C[M,N] = A[M,K] * Bw[N,K]^T + bias ----------------
// MODE 0: Q   -> Cb bf16 at [B,H,T,hd]
// MODE 1: K   -> Cf fp32 at [B,H,T,hd]  AND Cb bf16 at [B,H,T,hd]
// MODE 2: V   -> Cf fp32 at [B,H,T,hd]
// MODE 3: out -> Cf fp32 row-major [M,N]
template<int MODE>
__global__ __launch_bounds__(256, 2)
void gemm_bt(const unsigned short* __restrict__ A,
             const unsigned short* __restrict__ Bw,
             const float* __restrict__ bias,
             float* __restrict__ Cf,
             unsigned short* __restrict__ Cb,
             int M, int N, int K)
{
  constexpr int BK = 64;
  __shared__ unsigned short As[128 * BK];
  __shared__ unsigned short Bs[128 * BK];
  const int tid  = threadIdx.x;
  const int lane = tid & 63;
  const int wid  = tid >> 6;
  const int bm = blockIdx.y * 128;
  const int bn = blockIdx.x * 128;
  const int wr = (wid >> 1) * 64;     // wave row offset in tile
  const int wc = (wid & 1) * 64;      // wave col offset in tile
  const int lr = lane & 15;
  const int lk = (lane >> 4) * 8;
  // staging: thread t loads 16B: row = t>>3 (+i*32), seg = (t&7)*8 bf16
  const int srow = tid >> 3;
  const int scol = (tid & 7) * 8;
  const unsigned short* Ag = A  + (size_t)(bm + srow) * K + scol;
  const unsigned short* Bg = Bw + (size_t)(bn + srow) * K + scol;
  unsigned short* Asl = As + srow * BK + scol;
  unsigned short* Bsl = Bs + srow * BK + scol;

  f32x4 acc[4][4] = {};
  for (int k0 = 0; k0 < K; k0 += BK) {
#pragma unroll
    for (int i = 0; i < 4; ++i)
      gl_lds16(Ag + (size_t)(i * 32) * K + k0, Asl + i * 32 * BK);
#pragma unroll
    for (int i = 0; i < 4; ++i)
      gl_lds16(Bg + (size_t)(i * 32) * K + k0, Bsl + i * 32 * BK);
    __syncthreads();
#pragma unroll
    for (int kk = 0; kk < BK; kk += 32) {
      short8 af[4], bf[4];
#pragma unroll
      for (int m = 0; m < 4; ++m)
        af[m] = *(const short8*)&As[(wr + m * 16 + lr) * BK + kk + lk];
#pragma unroll
      for (int n = 0; n < 4; ++n)
        bf[n] = *(const short8*)&Bs[(wc + n * 16 + lr) * BK + kk + lk];
#pragma unroll
      for (int m = 0; m < 4; ++m)
#pragma unroll
        for (int n = 0; n < 4; ++n)
          acc[m][n] = __builtin_amdgcn_mfma_f32_16x16x32_bf16(af[m], bf[n], acc[m][n], 0, 0, 0);
    }
    __syncthreads();
  }

  const int rbase = (lane >> 4) * 4;
#pragma unroll
  for (int m = 0; m < 4; ++m) {
#pragma unroll
    for (int n = 0; n < 4; ++n) {
      const int col = bn + wc + n * 16 + lr;
      const float bb = bias[col];
#pragma unroll
      for (int r = 0; r < 4; ++r) {
        const int row = bm + wr + m * 16 + rbase + r;
        const float v = acc[m][n][r] + bb;
        if constexpr (MODE == 3) {
          Cf[(size_t)row * N + col] = v;
        } else {
          const int bI = row >> 11, t = row & 2047;
          const int h  = col >> 7,  e = col & 127;
          const size_t idx = (((size_t)(bI * 16 + h)) * 2048 + t) * 128 + e;
          if constexpr (MODE == 0) {
            Cb[idx] = f2bf(v);
          } else if constexpr (MODE == 1) {
            Cf[idx] = v; Cb[idx] = f2bf(v);
          } else {
            Cf[idx] = v;
          }
        }
      }
    }
  }
}

// ---------------- V [B,H,T,hd] fp32 -> Vt [B,H,hd,T] bf16 ----------------
__global__ void transpose_v(const float* __restrict__ V,
                            unsigned short* __restrict__ Vt) {
  __shared__ float tile[32][33];
  const int head = blockIdx.z;
  const int e0 = blockIdx.x * 32;
  const int t0 = blockIdx.y * 32;
  const int tx = threadIdx.x, ty = threadIdx.y;  // 32 x 8
  const float* src = V + (size_t)head * 2048 * 128;
  unsigned short* dst = Vt + (size_t)head * 128 * 2048;
#pragma unroll
  for (int i = 0; i < 32; i += 8)
    tile[ty + i][tx] = src[(size_t)(t0 + ty + i) * 128 + e0 + tx];
  __syncthreads();
#pragma unroll
  for (int i = 0; i < 32; i += 8)
    dst[(size_t)(e0 + ty + i) * 2048 + t0 + tx] = f2bf(tile[tx][ty + i]);
}

// ---------------- causal flash attention ----------------
// Qb,Kb: [B*H, T, 128] bf16 ; Vt: [B*H, 128, T] bf16 ; Ab out: [B*T, 2048] bf16
__global__ __launch_bounds__(256, 2)
void attn_fwd(const unsigned short* __restrict__ Qb,
              const unsigned short* __restrict__ Kb,
              const unsigned short* __restrict__ Vt,
              unsigned short* __restrict__ Ab)
{
  constexpr int T = 2048, HD = 128;
  constexpr float scale = 0.08838834764831843f;  // 1/sqrt(128)
  __shared__ unsigned short Pl[4][32][72];       // per-wave P tile, stride 72 (144B, 16B-aligned)
  const int bh = blockIdx.y;
  const int bI = bh >> 4, h = bh & 15;
  const int tid = threadIdx.x;
  const int wid = tid >> 6, lane = tid & 63;
  const int lr = lane & 15, lg = lane >> 4;
  const int qw = blockIdx.x * 128 + wid * 32;    // this wave's 32 q-rows
  const unsigned short* Qp = Qb + (size_t)bh * T * HD;
  const unsigned short* Kp = Kb + (size_t)bh * T * HD;
  const unsigned short* Vp = Vt + (size_t)bh * HD * T;

  // hoist Q fragments
  short8 qf[2][4];
#pragma unroll
  for (int m = 0; m < 2; ++m)
#pragma unroll
    for (int ks = 0; ks < 4; ++ks)
      qf[m][ks] = *(const short8*)&Qp[(size_t)(qw + m * 16 + lr) * HD + ks * 32 + lg * 8];

  f32x4 o[2][8] = {};
  float mrun[2][4], lrun[2][4];
#pragma unroll
  for (int m = 0; m < 2; ++m)
#pragma unroll
    for (int r = 0; r < 4; ++r) { mrun[m][r] = -1e30f; lrun[m][r] = 0.f; }

  const int ntile = (qw + 31) / 64 + 1;          // causal bound for this wave
  for (int kt = 0; kt < ntile; ++kt) {
    const int kv0 = kt * 64;
    // ---- S = Q K^T ----
    f32x4 s[2][4] = {};
#pragma unroll
    for (int ks = 0; ks < 4; ++ks) {
      short8 kf[4];
#pragma unroll
      for (int n = 0; n < 4; ++n)
        kf[n] = *(const short8*)&Kp[(size_t)(kv0 + n * 16 + lr) * HD + ks * 32 + lg * 8];
#pragma unroll
      for (int m = 0; m < 2; ++m)
#pragma unroll
        for (int n = 0; n < 4; ++n)
          s[m][n] = __builtin_amdgcn_mfma_f32_16x16x32_bf16(qf[m][ks], kf[n], s[m][n], 0, 0, 0);
    }
    // ---- scale + causal mask + tile row-max ----
    float tmax[2][4];
#pragma unroll
    for (int m = 0; m < 2; ++m)
#pragma unroll
      for (int r = 0; r < 4; ++r) tmax[m][r] = -1e30f;
#pragma unroll
    for (int m = 0; m < 2; ++m)
#pragma unroll
      for (int n = 0; n < 4; ++n) {
        const int kg = kv0 + n * 16 + lr;
#pragma unroll
        for (int r = 0; r < 4; ++r) {
          const int qg = qw + m * 16 + lg * 4 + r;
          float sv = s[m][n][r] * scale;
          sv = (kg <= qg) ? sv : -1e30f;
          s[m][n][r] = sv;
          tmax[m][r] = fmaxf(tmax[m][r], sv);
        }
      }
    // ---- online softmax update ----
#pragma unroll
    for (int m = 0; m < 2; ++m)
#pragma unroll
      for (int r = 0; r < 4; ++r) {
#pragma unroll
        for (int off = 8; off >= 1; off >>= 1)
          tmax[m][r] = fmaxf(tmax[m][r], __shfl_xor(tmax[m][r], off));
        const float mnew  = fmaxf(mrun[m][r], tmax[m][r]);
        const float alpha = __expf(mrun[m][r] - mnew);
        mrun[m][r] = mnew;
        lrun[m][r] *= alpha;
#pragma unroll
        for (int d = 0; d < 8; ++d) o[m][d][r] *= alpha;
      }
    // ---- P = exp(S - m), row-sums, stash P to per-wave LDS ----
#pragma unroll
    for (int m = 0; m < 2; ++m) {
      float ls[4] = {0.f, 0.f, 0.f, 0.f};
#pragma unroll
      for (int n = 0; n < 4; ++n)
#pragma unroll
        for (int r = 0; r < 4; ++r) {
          const float p = __expf(s[m][n][r] - mrun[m][r]);
          s[m][n][r] = p;
          ls[r] += p;
        }
#pragma unroll
      for (int r = 0; r < 4; ++r) {
#pragma unroll
        for (int off = 8; off >= 1; off >>= 1) ls[r] += __shfl_xor(ls[r], off);
        lrun[m][r] += ls[r];
      }
#pragma unroll
      for (int n = 0; n < 4; ++n)
#pragma unroll
        for (int r = 0; r < 4; ++r)
          Pl[wid][m * 16 + lg * 4 + r][n * 16 + lr] = f2bf(s[m][n][r]);
    }
    // ---- O += P V  (A-frag of P from LDS, B-frag of V^T from global) ----
#pragma unroll
    for (int ks2 = 0; ks2 < 2; ++ks2) {
      short8 pa[2];
#pragma unroll
      for (int m = 0; m < 2; ++m)
        pa[m] = *(const short8*)&Pl[wid][m * 16 + lr][ks2 * 32 + lg * 8];
#pragma unroll
      for (int dt = 0; dt < 8; ++dt) {
        const short8 vf = *(const short8*)&Vp[(size_t)(dt * 16 + lr) * T + kv0 + ks2 * 32 + lg * 8];
#pragma unroll
        for (int m = 0; m < 2; ++m)
          o[m][dt] = __builtin_amdgcn_mfma_f32_16x16x32_bf16(pa[m], vf, o[m][dt], 0, 0, 0);
      }
    }
  }
  // ---- normalize + store to attn-out [B*T, 2048] bf16 ----
#pragma unroll
  for (int m = 0; m < 2; ++m)
#pragma unroll
    for (int r = 0; r < 4; ++r) {
      const float inv = 1.0f / lrun[m][r];
      const int t = qw + m * 16 + lg * 4 + r;
      unsigned short* dst = Ab + ((size_t)(bI * 2048 + t)) * 2048 + h * 128;
#pragma unroll
      for (int dt = 0; dt < 8; ++dt)
        dst[dt * 16 + lr] = f2bf(o[m][dt][r] * inv);
    }
}

extern "C" void kernel_launch(void* const* d_in, const int* in_sizes, int n_in,
                              void* d_out, int out_size, void* d_ws, size_t ws_size,
                              hipStream_t stream) {
  const float* x  = (const float*)d_in[0];
  const float* wq = (const float*)d_in[1];
  const float* bq = (const float*)d_in[2];
  const float* wk = (const float*)d_in[3];
  const float* bk = (const float*)d_in[4];
  const float* wv = (const float*)d_in[5];
  const float* bv = (const float*)d_in[6];
  const float* wo = (const float*)d_in[7];
  const float* bo = (const float*)d_in[8];

  float* out  = (float*)d_out;                 // [B,T,d] fp32
  float* kout = out + (size_t)16777216;        // [B,H,T,hd] fp32
  float* vout = out + (size_t)33554432;        // [B,H,T,hd] fp32

  // workspace layout (bf16 elements); total 201.3 MB
  unsigned short* xb  = (unsigned short*)d_ws;       // x bf16 [8192,2048]
  unsigned short* wqb = xb  + 16777216;
  unsigned short* wkb = wqb + 4194304;
  unsigned short* wvb = wkb + 4194304;
  unsigned short* wob = wvb + 4194304;
  unsigned short* Qw  = wob + 4194304;               // Q bf16 [B,H,T,hd]
  unsigned short* Kw  = Qw  + 16777216;              // K bf16 [B,H,T,hd]
  unsigned short* Vtw = Kw  + 16777216;              // V^T bf16 [B,H,hd,T]
  unsigned short* Aw  = Vtw + 16777216;              // attn out bf16 [B*T, 2048]

  const int M = 8192, N = 2048, K = 2048;

  cvt_f32_bf16<<<1024, 256, 0, stream>>>(x,  xb,  4194304);
  cvt_f32_bf16<<<256,  256, 0, stream>>>(wq, wqb, 1048576);
  cvt_f32_bf16<<<256,  256, 0, stream>>>(wk, wkb, 1048576);
  cvt_f32_bf16<<<256,  256, 0, stream>>>(wv, wvb, 1048576);
  cvt_f32_bf16<<<256,  256, 0, stream>>>(wo, wob, 1048576);

  dim3 gg(N / 128, M / 128);
  gemm_bt<0><<<gg, 256, 0, stream>>>(xb, wqb, bq, nullptr, Qw, M, N, K);
  gemm_bt<1><<<gg, 256, 0, stream>>>(xb, wkb, bk, kout, Kw, M, N, K);
  gemm_bt<2><<<gg, 256, 0, stream>>>(xb, wvb, bv, vout, nullptr, M, N, K);

  transpose_v<<<dim3(4, 64, 64), dim3(32, 8), 0, stream>>>(vout, Vtw);

  attn_fwd<<<dim3(16, 64), 256, 0, stream>>>(Qw, Kw, Vtw, Aw);

  gemm_bt<3><<<gg, 256, 0, stream>>>(Aw, wob, bo, out, nullptr, M, N, K);
}

// Round 2
// 952.597 us; speedup vs baseline: 1.0891x; 1.0891x over previous
//
#include <hip/hip_runtime.h>
#include <hip/hip_bf16.h>
#include <stdint.h>

typedef __attribute__((ext_vector_type(8))) short short8;
typedef __attribute__((ext_vector_type(4))) float f32x4;

#define DEVI __device__ __forceinline__

DEVI unsigned short f2bf(float f) {
  union { float f; unsigned int u; } c; c.f = f;
  unsigned int u = c.u;
  u += 0x7fffu + ((u >> 16) & 1u);   // round-to-nearest-even
  return (unsigned short)(u >> 16);
}

DEVI void gl_lds16(const void* gsrc, void* lds) {
  __builtin_amdgcn_global_load_lds(
      (const __attribute__((address_space(1))) unsigned int*)gsrc,
      (__attribute__((address_space(3))) unsigned int*)lds, 16, 0, 0);
}

// ---------------- fp32 -> bf16 convert (vectorized) ----------------
__global__ void cvt_f32_bf16(const float* __restrict__ in,
                             unsigned short* __restrict__ out, int n4) {
  const int stride = gridDim.x * blockDim.x;
  for (int i = blockIdx.x * blockDim.x + threadIdx.x; i < n4; i += stride) {
    const float4 v = ((const float4*)in)[i];
    ushort4 o;
    o.x = f2bf(v.x); o.y = f2bf(v.y); o.z = f2bf(v.z); o.w = f2bf(v.w);
    ((ushort4*)out)[i] = o;
  }
}

// ---------------- bf16 GEMM:  C[M,N] = A[M,K] * Bw[N,K]^T + bias ----------------
// MODE 0: Q   -> Cb bf16 at [B,H,T,hd]
// MODE 1: K   -> Cf fp32 at [B,H,T,hd]  AND Cb bf16 at [B,H,T,hd]
// MODE 2: V   -> Cf fp32 at [B,H,T,hd]  AND Cb bf16 TRANSPOSED at [B,H,hd,T]
// MODE 3: out -> Cf fp32 row-major [M,N]
template<int MODE>
__global__ __launch_bounds__(256, 2)
void gemm_bt(const unsigned short* __restrict__ A,
             const unsigned short* __restrict__ Bw,
             const float* __restrict__ bias,
             float* __restrict__ Cf,
             unsigned short* __restrict__ Cb,
             int M, int N, int K)
{
  constexpr int BK = 64;
  __shared__ unsigned short As[128 * BK];
  __shared__ unsigned short Bs[128 * BK];
  const int tid  = threadIdx.x;
  const int lane = tid & 63;
  const int wid  = tid >> 6;
  const int bm = blockIdx.y * 128;
  const int bn = blockIdx.x * 128;
  const int wr = (wid >> 1) * 64;     // wave row offset in tile
  const int wc = (wid & 1) * 64;      // wave col offset in tile
  const int lr = lane & 15;
  const int lk = (lane >> 4) * 8;
  const int srow = tid >> 3;
  const int scol = (tid & 7) * 8;
  const unsigned short* Ag = A  + (size_t)(bm + srow) * K + scol;
  const unsigned short* Bg = Bw + (size_t)(bn + srow) * K + scol;
  unsigned short* Asl = As + srow * BK + scol;
  unsigned short* Bsl = Bs + srow * BK + scol;

  f32x4 acc[4][4] = {};
  for (int k0 = 0; k0 < K; k0 += BK) {
#pragma unroll
    for (int i = 0; i < 4; ++i)
      gl_lds16(Ag + (size_t)(i * 32) * K + k0, Asl + i * 32 * BK);
#pragma unroll
    for (int i = 0; i < 4; ++i)
      gl_lds16(Bg + (size_t)(i * 32) * K + k0, Bsl + i * 32 * BK);
    __syncthreads();
#pragma unroll
    for (int kk = 0; kk < BK; kk += 32) {
      short8 af[4], bf[4];
#pragma unroll
      for (int m = 0; m < 4; ++m)
        af[m] = *(const short8*)&As[(wr + m * 16 + lr) * BK + kk + lk];
#pragma unroll
      for (int n = 0; n < 4; ++n)
        bf[n] = *(const short8*)&Bs[(wc + n * 16 + lr) * BK + kk + lk];
#pragma unroll
      for (int m = 0; m < 4; ++m)
#pragma unroll
        for (int n = 0; n < 4; ++n)
          acc[m][n] = __builtin_amdgcn_mfma_f32_16x16x32_bf16(af[m], bf[n], acc[m][n], 0, 0, 0);
    }
    __syncthreads();
  }

  const int rbase = (lane >> 4) * 4;
#pragma unroll
  for (int m = 0; m < 4; ++m) {
#pragma unroll
    for (int n = 0; n < 4; ++n) {
      const int col = bn + wc + n * 16 + lr;
      const float bb = bias[col];
      const int row0 = bm + wr + m * 16 + rbase;
      float vv[4];
#pragma unroll
      for (int r = 0; r < 4; ++r) vv[r] = acc[m][n][r] + bb;
      if constexpr (MODE == 3) {
#pragma unroll
        for (int r = 0; r < 4; ++r) Cf[(size_t)(row0 + r) * N + col] = vv[r];
      } else {
        const int bI = row0 >> 11, t0 = row0 & 2047;
        const int h  = col >> 7,  e = col & 127;
        const size_t idx = (((size_t)(bI * 16 + h)) * 2048 + t0) * 128 + e;
        if constexpr (MODE == 0) {
#pragma unroll
          for (int r = 0; r < 4; ++r) Cb[idx + (size_t)r * 128] = f2bf(vv[r]);
        } else if constexpr (MODE == 1) {
#pragma unroll
          for (int r = 0; r < 4; ++r) {
            Cf[idx + (size_t)r * 128] = vv[r];
            Cb[idx + (size_t)r * 128] = f2bf(vv[r]);
          }
        } else {  // MODE 2: V fp32 + transposed bf16 [B,H,hd,T]
#pragma unroll
          for (int r = 0; r < 4; ++r) Cf[idx + (size_t)r * 128] = vv[r];
          ushort4 pk;
          pk.x = f2bf(vv[0]); pk.y = f2bf(vv[1]);
          pk.z = f2bf(vv[2]); pk.w = f2bf(vv[3]);
          *(ushort4*)&Cb[(((size_t)(bI * 16 + h)) * 128 + e) * 2048 + t0] = pk;
        }
      }
    }
  }
}

// ---------------- causal flash attention ----------------
// Qb,Kb: [B*H, T, 128] bf16 ; Vt: [B*H, 128, T] bf16 ; Ab out: [B*T, 2048] bf16
// Block: 4 waves x 32 q-rows = 128 q-rows. K/V tiles staged in LDS (shared),
// global_load_lds w/ pre-swizzled source, XOR-swizzled reads (T2).
__global__ __launch_bounds__(256, 3)
void attn_fwd(const unsigned short* __restrict__ Qb,
              const unsigned short* __restrict__ Kb,
              const unsigned short* __restrict__ Vt,
              unsigned short* __restrict__ Ab)
{
  constexpr int T = 2048, HD = 128;
  constexpr float scale = 0.08838834764831843f;  // 1/sqrt(128)
  __shared__ unsigned short Ks[64 * 128];        // [kv][d], swizzled, 16KB
  __shared__ unsigned short Vs[128 * 64];        // [d][kv], swizzled, 16KB
  __shared__ unsigned short Pl[4][32][72];       // per-wave P tile, 18KB
  const int bh = blockIdx.y;
  const int bI = bh >> 4, h = bh & 15;
  const int tid = threadIdx.x;
  const int wid = tid >> 6, lane = tid & 63;
  const int lr = lane & 15, lg = lane >> 4;
  const int sw = (lr & 7) << 3;                  // read-side XOR swizzle (elems)
  const int qi = (int)gridDim.x - 1 - (int)blockIdx.x;  // heavy blocks first
  const int qb0 = qi * 128;
  const int qw = qb0 + wid * 32;                 // this wave's 32 q-rows
  const unsigned short* Qp = Qb + (size_t)bh * T * HD;
  const unsigned short* Kp = Kb + (size_t)bh * T * HD;
  const unsigned short* Vp = Vt + (size_t)bh * HD * T;

  // hoist Q fragments
  short8 qf[2][4];
#pragma unroll
  for (int m = 0; m < 2; ++m)
#pragma unroll
    for (int ks = 0; ks < 4; ++ks)
      qf[m][ks] = *(const short8*)&Qp[(size_t)(qw + m * 16 + lr) * HD + ks * 32 + lg * 8];

  f32x4 o[2][8] = {};
  float mrun[2][4], lrun[2][4];
#pragma unroll
  for (int m = 0; m < 2; ++m)
#pragma unroll
    for (int r = 0; r < 4; ++r) { mrun[m][r] = -1e30f; lrun[m][r] = 0.f; }

  // staging lane geometry
  const int krow_i = lane >> 4;          // 0..3  (K: 4 rows/issue, 16 lanes/row)
  const int kcol   = (lane & 15) * 8;
  const int vrow_i = lane >> 3;          // 0..7  (V: 8 rows/issue, 8 lanes/row)
  const int vcol   = (lane & 7) * 8;

  const int ntile = 2 * qi + 2;          // block-level causal tile count
  for (int kt = 0; kt < ntile; ++kt) {
    const int kv0 = kt * 64;
    // ---- cooperative staging: K rows [kv0..kv0+63], Vt cols [kv0..kv0+63] ----
#pragma unroll
    for (int i = 0; i < 4; ++i) {
      const int rg = kv0 + wid * 16 + i * 4 + krow_i;
      gl_lds16(Kp + (size_t)rg * HD + (kcol ^ ((rg & 7) << 3)),
               &Ks[(wid * 16 + i * 4) * 128 + lane * 8]);
    }
#pragma unroll
    for (int i = 0; i < 4; ++i) {
      const int d = wid * 32 + i * 8 + vrow_i;
      gl_lds16(Vp + (size_t)d * T + kv0 + (vcol ^ ((d & 7) << 3)),
               &Vs[(wid * 32 + i * 8) * 64 + lane * 8]);
    }
    __syncthreads();

    if (kv0 <= qw + 31) {
      // ---- S = Q K^T from LDS ----
      f32x4 s[2][4] = {};
#pragma unroll
      for (int ks = 0; ks < 4; ++ks) {
        short8 kf[4];
#pragma unroll
        for (int n = 0; n < 4; ++n)
          kf[n] = *(const short8*)&Ks[(n * 16 + lr) * 128 + ((ks * 32 + lg * 8) ^ sw)];
#pragma unroll
        for (int m = 0; m < 2; ++m)
#pragma unroll
          for (int n = 0; n < 4; ++n)
            s[m][n] = __builtin_amdgcn_mfma_f32_16x16x32_bf16(qf[m][ks], kf[n], s[m][n], 0, 0, 0);
      }
      // ---- scale + causal mask + tile row-max ----
      float tmax[2][4];
#pragma unroll
      for (int m = 0; m < 2; ++m)
#pragma unroll
        for (int r = 0; r < 4; ++r) tmax[m][r] = -1e30f;
#pragma unroll
      for (int m = 0; m < 2; ++m)
#pragma unroll
        for (int n = 0; n < 4; ++n) {
          const int kg = kv0 + n * 16 + lr;
#pragma unroll
          for (int r = 0; r < 4; ++r) {
            const int qg = qw + m * 16 + lg * 4 + r;
            float sv = s[m][n][r] * scale;
            sv = (kg <= qg) ? sv : -1e30f;
            s[m][n][r] = sv;
            tmax[m][r] = fmaxf(tmax[m][r], sv);
          }
        }
      // ---- online softmax update ----
#pragma unroll
      for (int m = 0; m < 2; ++m)
#pragma unroll
        for (int r = 0; r < 4; ++r) {
#pragma unroll
          for (int off = 8; off >= 1; off >>= 1)
            tmax[m][r] = fmaxf(tmax[m][r], __shfl_xor(tmax[m][r], off));
          const float mnew  = fmaxf(mrun[m][r], tmax[m][r]);
          const float alpha = __expf(mrun[m][r] - mnew);
          mrun[m][r] = mnew;
          lrun[m][r] *= alpha;
#pragma unroll
          for (int d = 0; d < 8; ++d) o[m][d][r] *= alpha;
        }
      // ---- P = exp(S - m), row-sums, stash P to per-wave LDS ----
#pragma unroll
      for (int m = 0; m < 2; ++m) {
        float ls[4] = {0.f, 0.f, 0.f, 0.f};
#pragma unroll
        for (int n = 0; n < 4; ++n)
#pragma unroll
          for (int r = 0; r < 4; ++r) {
            const float p = __expf(s[m][n][r] - mrun[m][r]);
            s[m][n][r] = p;
            ls[r] += p;
          }
#pragma unroll
        for (int r = 0; r < 4; ++r) {
#pragma unroll
          for (int off = 8; off >= 1; off >>= 1) ls[r] += __shfl_xor(ls[r], off);
          lrun[m][r] += ls[r];
        }
#pragma unroll
        for (int n = 0; n < 4; ++n)
#pragma unroll
          for (int r = 0; r < 4; ++r)
            Pl[wid][m * 16 + lg * 4 + r][n * 16 + lr] = f2bf(s[m][n][r]);
      }
      // ---- O += P V  (A-frag from per-wave LDS, B-frag from swizzled Vs) ----
#pragma unroll
      for (int ks2 = 0; ks2 < 2; ++ks2) {
        short8 pa[2];
#pragma unroll
        for (int m = 0; m < 2; ++m)
          pa[m] = *(const short8*)&Pl[wid][m * 16 + lr][ks2 * 32 + lg * 8];
#pragma unroll
        for (int dt = 0; dt < 8; ++dt) {
          const short8 vf = *(const short8*)&Vs[(dt * 16 + lr) * 64 + ((ks2 * 32 + lg * 8) ^ sw)];
#pragma unroll
          for (int m = 0; m < 2; ++m)
            o[m][dt] = __builtin_amdgcn_mfma_f32_16x16x32_bf16(pa[m], vf, o[m][dt], 0, 0, 0);
        }
      }
    }
    __syncthreads();
  }
  // ---- normalize + store to attn-out [B*T, 2048] bf16 ----
#pragma unroll
  for (int m = 0; m < 2; ++m)
#pragma unroll
    for (int r = 0; r < 4; ++r) {
      const float inv = 1.0f / lrun[m][r];
      const int t = qw + m * 16 + lg * 4 + r;
      unsigned short* dst = Ab + ((size_t)(bI * 2048 + t)) * 2048 + h * 128;
#pragma unroll
      for (int dt = 0; dt < 8; ++dt)
        dst[dt * 16 + lr] = f2bf(o[m][dt][r] * inv);
    }
}

extern "C" void kernel_launch(void* const* d_in, const int* in_sizes, int n_in,
                              void* d_out, int out_size, void* d_ws, size_t ws_size,
                              hipStream_t stream) {
  const float* x  = (const float*)d_in[0];
  const float* wq = (const float*)d_in[1];
  const float* bq = (const float*)d_in[2];
  const float* wk = (const float*)d_in[3];
  const float* bk = (const float*)d_in[4];
  const float* wv = (const float*)d_in[5];
  const float* bv = (const float*)d_in[6];
  const float* wo = (const float*)d_in[7];
  const float* bo = (const float*)d_in[8];

  float* out  = (float*)d_out;                 // [B,T,d] fp32
  float* kout = out + (size_t)16777216;        // [B,H,T,hd] fp32
  float* vout = out + (size_t)33554432;        // [B,H,T,hd] fp32

  // workspace layout (bf16 elements)
  unsigned short* xb  = (unsigned short*)d_ws;       // x bf16 [8192,2048]
  unsigned short* wqb = xb  + 16777216;
  unsigned short* wkb = wqb + 4194304;
  unsigned short* wvb = wkb + 4194304;
  unsigned short* wob = wvb + 4194304;
  unsigned short* Qw  = wob + 4194304;               // Q bf16 [B,H,T,hd]
  unsigned short* Kw  = Qw  + 16777216;              // K bf16 [B,H,T,hd]
  unsigned short* Vtw = Kw  + 16777216;              // V^T bf16 [B,H,hd,T]
  unsigned short* Aw  = Vtw + 16777216;              // attn out bf16 [B*T, 2048]

  const int M = 8192, N = 2048, K = 2048;

  cvt_f32_bf16<<<1024, 256, 0, stream>>>(x,  xb,  4194304);
  cvt_f32_bf16<<<256,  256, 0, stream>>>(wq, wqb, 1048576);
  cvt_f32_bf16<<<256,  256, 0, stream>>>(wk, wkb, 1048576);
  cvt_f32_bf16<<<256,  256, 0, stream>>>(wv, wvb, 1048576);
  cvt_f32_bf16<<<256,  256, 0, stream>>>(wo, wob, 1048576);

  dim3 gg(N / 128, M / 128);
  gemm_bt<0><<<gg, 256, 0, stream>>>(xb, wqb, bq, nullptr, Qw, M, N, K);
  gemm_bt<1><<<gg, 256, 0, stream>>>(xb, wkb, bk, kout, Kw, M, N, K);
  gemm_bt<2><<<gg, 256, 0, stream>>>(xb, wvb, bv, vout, Vtw, M, N, K);

  attn_fwd<<<dim3(16, 64), 256, 0, stream>>>(Qw, Kw, Vtw, Aw);

  gemm_bt<3><<<gg, 256, 0, stream>>>(Aw, wob, bo, out, nullptr, M, N, K);
}

// Round 3
// 681.688 us; speedup vs baseline: 1.5219x; 1.3974x over previous
//
#include <hip/hip_runtime.h>
#include <hip/hip_bf16.h>
#include <stdint.h>

typedef __attribute__((ext_vector_type(8))) short short8;
typedef __attribute__((ext_vector_type(4))) float f32x4;

#define DEVI __device__ __forceinline__

DEVI unsigned short f2bf(float f) {
  union { float f; unsigned int u; } c; c.f = f;
  unsigned int u = c.u;
  u += 0x7fffu + ((u >> 16) & 1u);   // round-to-nearest-even
  return (unsigned short)(u >> 16);
}

DEVI void gl_lds16(const void* gsrc, void* lds) {
  __builtin_amdgcn_global_load_lds(
      (const __attribute__((address_space(1))) unsigned int*)gsrc,
      (__attribute__((address_space(3))) unsigned int*)lds, 16, 0, 0);
}

// ---------------- fp32 -> bf16 convert (vectorized) ----------------
__global__ void cvt_f32_bf16(const float* __restrict__ in,
                             unsigned short* __restrict__ out, int n4) {
  const int stride = gridDim.x * blockDim.x;
  for (int i = blockIdx.x * blockDim.x + threadIdx.x; i < n4; i += stride) {
    const float4 v = ((const float4*)in)[i];
    ushort4 o;
    o.x = f2bf(v.x); o.y = f2bf(v.y); o.z = f2bf(v.z); o.w = f2bf(v.w);
    ((ushort4*)out)[i] = o;
  }
}

// Fragment-packed layouts (per head, T=2048, HD=128, 262144 elems):
//  QK-pack:  off(t,e) = (t>>4)*2048 + (e>>5)*512 + (t&15)*32 + (e&31)
//   -> each (16-row t-tile, 32-col e-seg) fragment is 1KB contiguous.
//  V-pack:   off(d,t) = (t>>6)*8192 + (d>>4)*1024 + ((t>>5)&1)*512 + (d&15)*32 + (t&31)
//   -> each (16-row d-tile, 32-col kv-seg) B-fragment is 1KB contiguous.

// ---------------- bf16 GEMM:  C[M,N] = A[M,K] * Bw[N,K]^T + bias ----------------
// MODE 0: Q   -> Cb bf16 fragment-packed per head
// MODE 1: K   -> Cf fp32 at [B,H,T,hd]  AND Cb bf16 fragment-packed
// MODE 2: V   -> Cf fp32 at [B,H,T,hd]  AND Cb bf16 V-packed (transposed frags)
// MODE 3: out -> Cf fp32 row-major [M,N]
template<int MODE>
__global__ __launch_bounds__(256, 2)
void gemm_bt(const unsigned short* __restrict__ A,
             const unsigned short* __restrict__ Bw,
             const float* __restrict__ bias,
             float* __restrict__ Cf,
             unsigned short* __restrict__ Cb,
             int M, int N, int K)
{
  constexpr int BK = 64;
  __shared__ unsigned short As[128 * BK];
  __shared__ unsigned short Bs[128 * BK];
  const int tid  = threadIdx.x;
  const int lane = tid & 63;
  const int wid  = tid >> 6;
  const int bm = blockIdx.y * 128;
  const int bn = blockIdx.x * 128;
  const int wr = (wid >> 1) * 64;
  const int wc = (wid & 1) * 64;
  const int lr = lane & 15;
  const int lk = (lane >> 4) * 8;
  const int srow = tid >> 3;
  const int scol = (tid & 7) * 8;
  const unsigned short* Ag = A  + (size_t)(bm + srow) * K + scol;
  const unsigned short* Bg = Bw + (size_t)(bn + srow) * K + scol;
  unsigned short* Asl = As + srow * BK + scol;
  unsigned short* Bsl = Bs + srow * BK + scol;

  f32x4 acc[4][4] = {};
  for (int k0 = 0; k0 < K; k0 += BK) {
#pragma unroll
    for (int i = 0; i < 4; ++i)
      gl_lds16(Ag + (size_t)(i * 32) * K + k0, Asl + i * 32 * BK);
#pragma unroll
    for (int i = 0; i < 4; ++i)
      gl_lds16(Bg + (size_t)(i * 32) * K + k0, Bsl + i * 32 * BK);
    __syncthreads();
#pragma unroll
    for (int kk = 0; kk < BK; kk += 32) {
      short8 af[4], bf[4];
#pragma unroll
      for (int m = 0; m < 4; ++m)
        af[m] = *(const short8*)&As[(wr + m * 16 + lr) * BK + kk + lk];
#pragma unroll
      for (int n = 0; n < 4; ++n)
        bf[n] = *(const short8*)&Bs[(wc + n * 16 + lr) * BK + kk + lk];
#pragma unroll
      for (int m = 0; m < 4; ++m)
#pragma unroll
        for (int n = 0; n < 4; ++n)
          acc[m][n] = __builtin_amdgcn_mfma_f32_16x16x32_bf16(af[m], bf[n], acc[m][n], 0, 0, 0);
    }
    __syncthreads();
  }

  const int rbase = (lane >> 4) * 4;
#pragma unroll
  for (int m = 0; m < 4; ++m) {
#pragma unroll
    for (int n = 0; n < 4; ++n) {
      const int col = bn + wc + n * 16 + lr;
      const float bb = bias[col];
      const int row0 = bm + wr + m * 16 + rbase;
      float vv[4];
#pragma unroll
      for (int r = 0; r < 4; ++r) vv[r] = acc[m][n][r] + bb;
      if constexpr (MODE == 3) {
#pragma unroll
        for (int r = 0; r < 4; ++r) Cf[(size_t)(row0 + r) * N + col] = vv[r];
      } else {
        const int bI = row0 >> 11, t0 = row0 & 2047;
        const int h  = col >> 7,  e = col & 127;
        const size_t hb  = ((size_t)(bI * 16 + h)) * 262144;
        const size_t idx = hb + (size_t)t0 * 128 + e;   // row-major [t][e]
        if constexpr (MODE == 0) {
          const size_t qb = hb + (size_t)(t0 >> 4) * 2048 + (e >> 5) * 512
                          + (t0 & 15) * 32 + (e & 31);
#pragma unroll
          for (int r = 0; r < 4; ++r) Cb[qb + (size_t)r * 32] = f2bf(vv[r]);
        } else if constexpr (MODE == 1) {
          const size_t qb = hb + (size_t)(t0 >> 4) * 2048 + (e >> 5) * 512
                          + (t0 & 15) * 32 + (e & 31);
#pragma unroll
          for (int r = 0; r < 4; ++r) {
            Cf[idx + (size_t)r * 128] = vv[r];
            Cb[qb + (size_t)r * 32] = f2bf(vv[r]);
          }
        } else {  // MODE 2: V fp32 row-major + V-packed bf16 fragments
#pragma unroll
          for (int r = 0; r < 4; ++r) Cf[idx + (size_t)r * 128] = vv[r];
          const size_t vb = hb + (size_t)(t0 >> 6) * 8192 + (size_t)(e >> 4) * 1024
                          + ((t0 >> 5) & 1) * 512 + (e & 15) * 32 + (t0 & 31);
          ushort4 pk;
          pk.x = f2bf(vv[0]); pk.y = f2bf(vv[1]);
          pk.z = f2bf(vv[2]); pk.w = f2bf(vv[3]);
          *(ushort4*)&Cb[vb] = pk;
        }
      }
    }
  }
}

// ---------------- causal flash attention, barrier-free ----------------
// One wave (64 threads) per block; each wave owns 32 q-rows of one head.
// Q/K fragment-packed, V transposed-fragment-packed: every MFMA fragment
// is a single coalesced 1KB global load (L2-resident per head).
__global__ __launch_bounds__(64, 2)
void attn_fwd(const unsigned short* __restrict__ Qf,
              const unsigned short* __restrict__ Kf,
              const unsigned short* __restrict__ Vf,
              unsigned short* __restrict__ Ab)
{
  constexpr float scale = 0.08838834764831843f;  // 1/sqrt(128)
  __shared__ unsigned short Pl[32][72];

  // XCD-aware swizzle: 4096 blocks -> 8 chunks of 512 (8 heads each);
  // within a head, heavy (high-qi) q-strips first.
  const int bid = blockIdx.x;
  const int sw  = (bid & 7) * 512 + (bid >> 3);
  const int bh  = sw >> 6;
  const int qi  = 63 - (sw & 63);
  const int qw  = qi * 32;
  const int bI = bh >> 4, h = bh & 15;
  const int lane = threadIdx.x;
  const int lr = lane & 15, lg = lane >> 4;
  const int lfo = lr * 32 + lg * 8;              // per-lane offset within 1KB frag

  const unsigned short* Qp = Qf + (size_t)bh * 262144 + (size_t)(qw >> 4) * 2048;
  const unsigned short* Kp = Kf + (size_t)bh * 262144;
  const unsigned short* Vp = Vf + (size_t)bh * 262144;

  short8 qf[2][4];
#pragma unroll
  for (int m = 0; m < 2; ++m)
#pragma unroll
    for (int ks = 0; ks < 4; ++ks)
      qf[m][ks] = *(const short8*)&Qp[m * 2048 + ks * 512 + lfo];

  f32x4 o[2][8] = {};
  float mrun[2][4], lrun[2][4];
#pragma unroll
  for (int m = 0; m < 2; ++m)
#pragma unroll
    for (int r = 0; r < 4; ++r) { mrun[m][r] = -1e30f; lrun[m][r] = 0.f; }

  const int nfull = qw >> 6;                     // tiles before the diagonal tile
  for (int kt = 0; kt <= nfull; ++kt) {
    const int kv0 = kt * 64;
    const bool diag = (kt == nfull);
    const unsigned short* Kt = Kp + (size_t)(kv0 >> 4) * 2048;
    const unsigned short* Vt = Vp + (size_t)(kv0 >> 6) * 8192;

    // ---- S = Q K^T : 16 coalesced K-frag loads, then 32 MFMA ----
    short8 kf[4][4];
#pragma unroll
    for (int n = 0; n < 4; ++n)
#pragma unroll
      for (int ks = 0; ks < 4; ++ks)
        kf[n][ks] = *(const short8*)&Kt[n * 2048 + ks * 512 + lfo];
    f32x4 s[2][4] = {};
#pragma unroll
    for (int ks = 0; ks < 4; ++ks)
#pragma unroll
      for (int m = 0; m < 2; ++m)
#pragma unroll
        for (int n = 0; n < 4; ++n)
          s[m][n] = __builtin_amdgcn_mfma_f32_16x16x32_bf16(qf[m][ks], kf[n][ks], s[m][n], 0, 0, 0);

    // ---- issue all V-frag loads now; latency hides under softmax ----
    short8 vf[2][8];
#pragma unroll
    for (int ks2 = 0; ks2 < 2; ++ks2)
#pragma unroll
      for (int dt = 0; dt < 8; ++dt)
        vf[ks2][dt] = *(const short8*)&Vt[dt * 1024 + ks2 * 512 + lfo];

    // ---- scale (+ mask on diagonal tile) + tile row-max ----
    float tmax[2][4];
#pragma unroll
    for (int m = 0; m < 2; ++m)
#pragma unroll
      for (int r = 0; r < 4; ++r) tmax[m][r] = -1e30f;
#pragma unroll
    for (int m = 0; m < 2; ++m)
#pragma unroll
      for (int n = 0; n < 4; ++n) {
        const int kg = kv0 + n * 16 + lr;
#pragma unroll
        for (int r = 0; r < 4; ++r) {
          float sv = s[m][n][r] * scale;
          if (diag) {
            const int qg = qw + m * 16 + lg * 4 + r;
            sv = (kg <= qg) ? sv : -1e30f;
          }
          s[m][n][r] = sv;
          tmax[m][r] = fmaxf(tmax[m][r], sv);
        }
      }
    // ---- online softmax update ----
#pragma unroll
    for (int m = 0; m < 2; ++m)
#pragma unroll
      for (int r = 0; r < 4; ++r) {
#pragma unroll
        for (int off = 8; off >= 1; off >>= 1)
          tmax[m][r] = fmaxf(tmax[m][r], __shfl_xor(tmax[m][r], off));
        const float mnew  = fmaxf(mrun[m][r], tmax[m][r]);
        const float alpha = __expf(mrun[m][r] - mnew);
        mrun[m][r] = mnew;
        lrun[m][r] *= alpha;
#pragma unroll
        for (int d = 0; d < 8; ++d) o[m][d][r] *= alpha;
      }
    // ---- P = exp(S - m), row-sums, stash P to LDS ----
#pragma unroll
    for (int m = 0; m < 2; ++m) {
      float ls[4] = {0.f, 0.f, 0.f, 0.f};
#pragma unroll
      for (int n = 0; n < 4; ++n)
#pragma unroll
        for (int r = 0; r < 4; ++r) {
          const float p = __expf(s[m][n][r] - mrun[m][r]);
          s[m][n][r] = p;
          ls[r] += p;
        }
#pragma unroll
      for (int r = 0; r < 4; ++r) {
#pragma unroll
        for (int off = 8; off >= 1; off >>= 1) ls[r] += __shfl_xor(ls[r], off);
        lrun[m][r] += ls[r];
      }
#pragma unroll
      for (int n = 0; n < 4; ++n)
#pragma unroll
        for (int r = 0; r < 4; ++r)
          Pl[m * 16 + lg * 4 + r][n * 16 + lr] = f2bf(s[m][n][r]);
    }
    // ---- O += P V ----
#pragma unroll
    for (int ks2 = 0; ks2 < 2; ++ks2) {
      short8 pa[2];
#pragma unroll
      for (int m = 0; m < 2; ++m)
        pa[m] = *(const short8*)&Pl[m * 16 + lr][ks2 * 32 + lg * 8];
#pragma unroll
      for (int dt = 0; dt < 8; ++dt)
#pragma unroll
        for (int m = 0; m < 2; ++m)
          o[m][dt] = __builtin_amdgcn_mfma_f32_16x16x32_bf16(pa[m], vf[ks2][dt], o[m][dt], 0, 0, 0);
    }
  }
  // ---- normalize + store to attn-out [B*T, 2048] bf16 ----
#pragma unroll
  for (int m = 0; m < 2; ++m)
#pragma unroll
    for (int r = 0; r < 4; ++r) {
      const float inv = 1.0f / lrun[m][r];
      const int t = qw + m * 16 + lg * 4 + r;
      unsigned short* dst = Ab + ((size_t)(bI * 2048 + t)) * 2048 + h * 128;
#pragma unroll
      for (int dt = 0; dt < 8; ++dt)
        dst[dt * 16 + lr] = f2bf(o[m][dt][r] * inv);
    }
}

extern "C" void kernel_launch(void* const* d_in, const int* in_sizes, int n_in,
                              void* d_out, int out_size, void* d_ws, size_t ws_size,
                              hipStream_t stream) {
  const float* x  = (const float*)d_in[0];
  const float* wq = (const float*)d_in[1];
  const float* bq = (const float*)d_in[2];
  const float* wk = (const float*)d_in[3];
  const float* bk = (const float*)d_in[4];
  const float* wv = (const float*)d_in[5];
  const float* bv = (const float*)d_in[6];
  const float* wo = (const float*)d_in[7];
  const float* bo = (const float*)d_in[8];

  float* out  = (float*)d_out;                 // [B,T,d] fp32
  float* kout = out + (size_t)16777216;        // [B,H,T,hd] fp32
  float* vout = out + (size_t)33554432;        // [B,H,T,hd] fp32

  // workspace layout (bf16 elements)
  unsigned short* xb  = (unsigned short*)d_ws;       // x bf16 [8192,2048]
  unsigned short* wqb = xb  + 16777216;
  unsigned short* wkb = wqb + 4194304;
  unsigned short* wvb = wkb + 4194304;
  unsigned short* wob = wvb + 4194304;
  unsigned short* Qw  = wob + 4194304;               // Q bf16 fragment-packed
  unsigned short* Kw  = Qw  + 16777216;              // K bf16 fragment-packed
  unsigned short* Vfw = Kw  + 16777216;              // V bf16 V-packed
  unsigned short* Aw  = Vfw + 16777216;              // attn out bf16 [B*T, 2048]

  const int M = 8192, N = 2048, K = 2048;

  cvt_f32_bf16<<<1024, 256, 0, stream>>>(x,  xb,  4194304);
  cvt_f32_bf16<<<256,  256, 0, stream>>>(wq, wqb, 1048576);
  cvt_f32_bf16<<<256,  256, 0, stream>>>(wk, wkb, 1048576);
  cvt_f32_bf16<<<256,  256, 0, stream>>>(wv, wvb, 1048576);
  cvt_f32_bf16<<<256,  256, 0, stream>>>(wo, wob, 1048576);

  dim3 gg(N / 128, M / 128);
  gemm_bt<0><<<gg, 256, 0, stream>>>(xb, wqb, bq, nullptr, Qw, M, N, K);
  gemm_bt<1><<<gg, 256, 0, stream>>>(xb, wkb, bk, kout, Kw, M, N, K);
  gemm_bt<2><<<gg, 256, 0, stream>>>(xb, wvb, bv, vout, Vfw, M, N, K);

  attn_fwd<<<dim3(4096), 64, 0, stream>>>(Qw, Kw, Vfw, Aw);

  gemm_bt<3><<<gg, 256, 0, stream>>>(Aw, wob, bo, out, nullptr, M, N, K);
}

// Round 4
// 610.009 us; speedup vs baseline: 1.7008x; 1.1175x over previous
//
#include <hip/hip_runtime.h>
#include <hip/hip_bf16.h>
#include <stdint.h>

typedef __attribute__((ext_vector_type(8))) short short8;
typedef __attribute__((ext_vector_type(4))) float f32x4;

#define DEVI __device__ __forceinline__

DEVI unsigned short f2bf(float f) {
  union { float f; unsigned int u; } c; c.f = f;
  unsigned int u = c.u;
  u += 0x7fffu + ((u >> 16) & 1u);   // round-to-nearest-even
  return (unsigned short)(u >> 16);
}

DEVI void gl_lds16(const void* gsrc, void* lds) {
  __builtin_amdgcn_global_load_lds(
      (const __attribute__((address_space(1))) unsigned int*)gsrc,
      (__attribute__((address_space(3))) unsigned int*)lds, 16, 0, 0);
}

// ---------------- fp32 -> bf16 convert (vectorized) ----------------
__global__ void cvt_f32_bf16(const float* __restrict__ in,
                             unsigned short* __restrict__ out, int n4) {
  const int stride = gridDim.x * blockDim.x;
  for (int i = blockIdx.x * blockDim.x + threadIdx.x; i < n4; i += stride) {
    const float4 v = ((const float4*)in)[i];
    ushort4 o;
    o.x = f2bf(v.x); o.y = f2bf(v.y); o.z = f2bf(v.z); o.w = f2bf(v.w);
    ((ushort4*)out)[i] = o;
  }
}

// Fragment-packed layouts (per head, T=2048, HD=128, 262144 elems):
//  QK-pack:  off(t,e) = (t>>4)*2048 + (e>>5)*512 + (t&15)*32 + (e&31)
//  V-pack:   off(d,t) = (t>>6)*8192 + (d>>4)*1024 + ((t>>5)&1)*512 + (d&15)*32 + (t&31)

// ---------------- 256x256 deep-pipelined bf16 GEMM ----------------
// C[M,N] = A[M,K] * Bw[N,K]^T + bias.
// MODE 0: fused QKV (N=6144): col panel 0 -> Q packed, 1 -> K fp32+packed,
//         2 -> V fp32+packed.
// MODE 3: fp32 row-major C (out projection).
// 8 waves (2M x 4N), per-wave 128x64 out, BK=32, 4-deep LDS ring,
// counted vmcnt (never 0 in steady state), raw barriers, frag-packed LDS.
template<int MODE>
__global__ __launch_bounds__(512, 2)
void gemm256(const unsigned short* __restrict__ A,
             const unsigned short* __restrict__ Bw,
             const float* __restrict__ bq,
             const float* __restrict__ bk,
             const float* __restrict__ bv,
             float* __restrict__ Kf,
             float* __restrict__ Vf,
             unsigned short* __restrict__ Qpk,
             unsigned short* __restrict__ Kpk,
             unsigned short* __restrict__ Vpk,
             float* __restrict__ Cf,
             int M, int N, int K)
{
  __shared__ unsigned short S[4][16384];   // per buf: A frags [0,8192), B frags [8192,16384)
  const int tid  = threadIdx.x;
  const int lane = tid & 63;
  const int wid  = tid >> 6;
  const int l15  = lane & 15, l4 = lane >> 4;

  // XCD-bijective chunked swizzle; column-panel-major within chunk.
  const int chunk = gridDim.x >> 3;
  const int q  = blockIdx.x;
  const int wg = (q & 7) * chunk + (q >> 3);
  const int bm = (wg & 31) * 256;
  const int bn = (wg >> 5) * 256;

  // staging sources: wave wid stages frags wid and wid+8 of each operand;
  // lane l supplies row (frag*16 + l&15), k-seg (l>>4)*8  -> lands at
  // LDS frag*1024B + lane*16B == fragment-packed, conflict-free reads.
  const unsigned short* Asrc0 = A  + (size_t)(bm + wid * 16 + l15) * K + l4 * 8;
  const unsigned short* Asrc1 = A  + (size_t)(bm + (wid + 8) * 16 + l15) * K + l4 * 8;
  const unsigned short* Bsrc0 = Bw + (size_t)(bn + wid * 16 + l15) * K + l4 * 8;
  const unsigned short* Bsrc1 = Bw + (size_t)(bn + (wid + 8) * 16 + l15) * K + l4 * 8;

  const int nt = K >> 5;                    // K-tiles of 32
  // prologue: stage tiles 0,1,2
#pragma unroll
  for (int kt = 0; kt < 3; ++kt) {
    unsigned short* Sd = S[kt];
    const int koff = kt * 32;
    gl_lds16(Asrc0 + koff, &Sd[wid * 512 + lane * 8]);
    gl_lds16(Asrc1 + koff, &Sd[(wid + 8) * 512 + lane * 8]);
    gl_lds16(Bsrc0 + koff, &Sd[8192 + wid * 512 + lane * 8]);
    gl_lds16(Bsrc1 + koff, &Sd[8192 + (wid + 8) * 512 + lane * 8]);
  }

  f32x4 acc[8][4] = {};
  const int afbase = (wid >> 2) * 4096 + lane * 8;          // A frag base (elems)
  const int bfbase = 8192 + (wid & 3) * 2048 + lane * 8;    // B frag base

  for (int kt = 0; kt < nt; ++kt) {
    const int rem = nt - 1 - kt;
    if (rem >= 2)      asm volatile("s_waitcnt vmcnt(8)" ::: "memory");
    else if (rem == 1) asm volatile("s_waitcnt vmcnt(4)" ::: "memory");
    else               asm volatile("s_waitcnt vmcnt(0)" ::: "memory");
    asm volatile("s_waitcnt lgkmcnt(0)" ::: "memory");
    __builtin_amdgcn_s_barrier();
    __builtin_amdgcn_sched_barrier(0);

    const unsigned short* Sb = S[kt & 3];
    short8 af[8], bf[4];
#pragma unroll
    for (int m = 0; m < 8; ++m) af[m] = *(const short8*)&Sb[afbase + m * 512];
#pragma unroll
    for (int n = 0; n < 4; ++n) bf[n] = *(const short8*)&Sb[bfbase + n * 512];

    if (kt + 3 < nt) {
      unsigned short* Sd = S[(kt + 3) & 3];
      const int koff = (kt + 3) * 32;
      gl_lds16(Asrc0 + koff, &Sd[wid * 512 + lane * 8]);
      gl_lds16(Asrc1 + koff, &Sd[(wid + 8) * 512 + lane * 8]);
      gl_lds16(Bsrc0 + koff, &Sd[8192 + wid * 512 + lane * 8]);
      gl_lds16(Bsrc1 + koff, &Sd[8192 + (wid + 8) * 512 + lane * 8]);
    }

    __builtin_amdgcn_s_setprio(1);
#pragma unroll
    for (int m = 0; m < 8; ++m)
#pragma unroll
      for (int n = 0; n < 4; ++n)
        acc[m][n] = __builtin_amdgcn_mfma_f32_16x16x32_bf16(af[m], bf[n], acc[m][n], 0, 0, 0);
    __builtin_amdgcn_s_setprio(0);
  }

  // ---- epilogue ----
  const int rbase = l4 * 4;
#pragma unroll
  for (int m = 0; m < 8; ++m) {
    const int row0 = bm + (wid >> 2) * 128 + m * 16 + rbase;
#pragma unroll
    for (int n = 0; n < 4; ++n) {
      const int col6 = bn + (wid & 3) * 64 + n * 16 + l15;
      if constexpr (MODE == 3) {
        const float bb = bq[col6];
#pragma unroll
        for (int r = 0; r < 4; ++r)
          Cf[(size_t)(row0 + r) * N + col6] = acc[m][n][r] + bb;
      } else {
        const int sel = col6 >> 11;
        const int col = col6 & 2047;
        const float bb = (sel == 0 ? bq : sel == 1 ? bk : bv)[col];
        float vv[4];
#pragma unroll
        for (int r = 0; r < 4; ++r) vv[r] = acc[m][n][r] + bb;
        const int bI = row0 >> 11, t0 = row0 & 2047;
        const int h = col >> 7, e = col & 127;
        const size_t hb = ((size_t)(bI * 16 + h)) * 262144;
        if (sel == 0) {
          const size_t qb = hb + (size_t)(t0 >> 4) * 2048 + (e >> 5) * 512
                          + (t0 & 15) * 32 + (e & 31);
#pragma unroll
          for (int r = 0; r < 4; ++r) Qpk[qb + (size_t)r * 32] = f2bf(vv[r]);
        } else if (sel == 1) {
          const size_t idx = hb + (size_t)t0 * 128 + e;
          const size_t qb = hb + (size_t)(t0 >> 4) * 2048 + (e >> 5) * 512
                          + (t0 & 15) * 32 + (e & 31);
#pragma unroll
          for (int r = 0; r < 4; ++r) {
            Kf[idx + (size_t)r * 128] = vv[r];
            Kpk[qb + (size_t)r * 32] = f2bf(vv[r]);
          }
        } else {
          const size_t idx = hb + (size_t)t0 * 128 + e;
#pragma unroll
          for (int r = 0; r < 4; ++r) Vf[idx + (size_t)r * 128] = vv[r];
          const size_t vb = hb + (size_t)(t0 >> 6) * 8192 + (size_t)(e >> 4) * 1024
                          + ((t0 >> 5) & 1) * 512 + (e & 15) * 32 + (t0 & 31);
          ushort4 pk;
          pk.x = f2bf(vv[0]); pk.y = f2bf(vv[1]);
          pk.z = f2bf(vv[2]); pk.w = f2bf(vv[3]);
          *(ushort4*)&Vpk[vb] = pk;
        }
      }
    }
  }
}

// ---------------- causal flash attention, barrier-free ----------------
__global__ __launch_bounds__(64, 2)
void attn_fwd(const unsigned short* __restrict__ Qf,
              const unsigned short* __restrict__ Kf,
              const unsigned short* __restrict__ Vf,
              unsigned short* __restrict__ Ab)
{
  constexpr float scale = 0.08838834764831843f;  // 1/sqrt(128)
  __shared__ unsigned short Pl[32][72];

  const int bid = blockIdx.x;
  const int sw  = (bid & 7) * 512 + (bid >> 3);
  const int bh  = sw >> 6;
  const int qi  = 63 - (sw & 63);
  const int qw  = qi * 32;
  const int bI = bh >> 4, h = bh & 15;
  const int lane = threadIdx.x;
  const int lr = lane & 15, lg = lane >> 4;
  const int lfo = lr * 32 + lg * 8;

  const unsigned short* Qp = Qf + (size_t)bh * 262144 + (size_t)(qw >> 4) * 2048;
  const unsigned short* Kp = Kf + (size_t)bh * 262144;
  const unsigned short* Vp = Vf + (size_t)bh * 262144;

  short8 qf[2][4];
#pragma unroll
  for (int m = 0; m < 2; ++m)
#pragma unroll
    for (int ks = 0; ks < 4; ++ks)
      qf[m][ks] = *(const short8*)&Qp[m * 2048 + ks * 512 + lfo];

  f32x4 o[2][8] = {};
  float mrun[2][4], lrun[2][4];
#pragma unroll
  for (int m = 0; m < 2; ++m)
#pragma unroll
    for (int r = 0; r < 4; ++r) { mrun[m][r] = -1e30f; lrun[m][r] = 0.f; }

  const int nfull = qw >> 6;
  for (int kt = 0; kt <= nfull; ++kt) {
    const int kv0 = kt * 64;
    const bool diag = (kt == nfull);
    const unsigned short* Kt = Kp + (size_t)(kv0 >> 4) * 2048;
    const unsigned short* Vt = Vp + (size_t)(kv0 >> 6) * 8192;

    short8 kf[4][4];
#pragma unroll
    for (int n = 0; n < 4; ++n)
#pragma unroll
      for (int ks = 0; ks < 4; ++ks)
        kf[n][ks] = *(const short8*)&Kt[n * 2048 + ks * 512 + lfo];
    f32x4 s[2][4] = {};
#pragma unroll
    for (int ks = 0; ks < 4; ++ks)
#pragma unroll
      for (int m = 0; m < 2; ++m)
#pragma unroll
        for (int n = 0; n < 4; ++n)
          s[m][n] = __builtin_amdgcn_mfma_f32_16x16x32_bf16(qf[m][ks], kf[n][ks], s[m][n], 0, 0, 0);

    short8 vf[2][8];
#pragma unroll
    for (int ks2 = 0; ks2 < 2; ++ks2)
#pragma unroll
      for (int dt = 0; dt < 8; ++dt)
        vf[ks2][dt] = *(const short8*)&Vt[dt * 1024 + ks2 * 512 + lfo];

    float tmax[2][4];
#pragma unroll
    for (int m = 0; m < 2; ++m)
#pragma unroll
      for (int r = 0; r < 4; ++r) tmax[m][r] = -1e30f;
#pragma unroll
    for (int m = 0; m < 2; ++m)
#pragma unroll
      for (int n = 0; n < 4; ++n) {
        const int kg = kv0 + n * 16 + lr;
#pragma unroll
        for (int r = 0; r < 4; ++r) {
          float sv = s[m][n][r] * scale;
          if (diag) {
            const int qg = qw + m * 16 + lg * 4 + r;
            sv = (kg <= qg) ? sv : -1e30f;
          }
          s[m][n][r] = sv;
          tmax[m][r] = fmaxf(tmax[m][r], sv);
        }
      }
#pragma unroll
    for (int m = 0; m < 2; ++m)
#pragma unroll
      for (int r = 0; r < 4; ++r) {
#pragma unroll
        for (int off = 8; off >= 1; off >>= 1)
          tmax[m][r] = fmaxf(tmax[m][r], __shfl_xor(tmax[m][r], off));
        const float mnew  = fmaxf(mrun[m][r], tmax[m][r]);
        const float alpha = __expf(mrun[m][r] - mnew);
        mrun[m][r] = mnew;
        lrun[m][r] *= alpha;
#pragma unroll
        for (int d = 0; d < 8; ++d) o[m][d][r] *= alpha;
      }
#pragma unroll
    for (int m = 0; m < 2; ++m) {
      float ls[4] = {0.f, 0.f, 0.f, 0.f};
#pragma unroll
      for (int n = 0; n < 4; ++n)
#pragma unroll
        for (int r = 0; r < 4; ++r) {
          const float p = __expf(s[m][n][r] - mrun[m][r]);
          s[m][n][r] = p;
          ls[r] += p;
        }
#pragma unroll
      for (int r = 0; r < 4; ++r) {
#pragma unroll
        for (int off = 8; off >= 1; off >>= 1) ls[r] += __shfl_xor(ls[r], off);
        lrun[m][r] += ls[r];
      }
#pragma unroll
      for (int n = 0; n < 4; ++n)
#pragma unroll
        for (int r = 0; r < 4; ++r)
          Pl[m * 16 + lg * 4 + r][n * 16 + lr] = f2bf(s[m][n][r]);
    }
#pragma unroll
    for (int ks2 = 0; ks2 < 2; ++ks2) {
      short8 pa[2];
#pragma unroll
      for (int m = 0; m < 2; ++m)
        pa[m] = *(const short8*)&Pl[m * 16 + lr][ks2 * 32 + lg * 8];
#pragma unroll
      for (int dt = 0; dt < 8; ++dt)
#pragma unroll
        for (int m = 0; m < 2; ++m)
          o[m][dt] = __builtin_amdgcn_mfma_f32_16x16x32_bf16(pa[m], vf[ks2][dt], o[m][dt], 0, 0, 0);
    }
  }
#pragma unroll
  for (int m = 0; m < 2; ++m)
#pragma unroll
    for (int r = 0; r < 4; ++r) {
      const float inv = 1.0f / lrun[m][r];
      const int t = qw + m * 16 + lg * 4 + r;
      unsigned short* dst = Ab + ((size_t)(bI * 2048 + t)) * 2048 + h * 128;
#pragma unroll
      for (int dt = 0; dt < 8; ++dt)
        dst[dt * 16 + lr] = f2bf(o[m][dt][r] * inv);
    }
}

extern "C" void kernel_launch(void* const* d_in, const int* in_sizes, int n_in,
                              void* d_out, int out_size, void* d_ws, size_t ws_size,
                              hipStream_t stream) {
  const float* x  = (const float*)d_in[0];
  const float* wq = (const float*)d_in[1];
  const float* bq = (const float*)d_in[2];
  const float* wk = (const float*)d_in[3];
  const float* bk = (const float*)d_in[4];
  const float* wv = (const float*)d_in[5];
  const float* bv = (const float*)d_in[6];
  const float* wo = (const float*)d_in[7];
  const float* bo = (const float*)d_in[8];

  float* out  = (float*)d_out;                 // [B,T,d] fp32
  float* kout = out + (size_t)16777216;        // [B,H,T,hd] fp32
  float* vout = out + (size_t)33554432;        // [B,H,T,hd] fp32

  // workspace layout (bf16 elements)
  unsigned short* xb  = (unsigned short*)d_ws;       // x bf16 [8192,2048]
  unsigned short* wqb = xb  + 16777216;              // wq/wk/wv contiguous = [6144,2048]
  unsigned short* wkb = wqb + 4194304;
  unsigned short* wvb = wkb + 4194304;
  unsigned short* wob = wvb + 4194304;
  unsigned short* Qw  = wob + 4194304;               // Q bf16 fragment-packed
  unsigned short* Kw  = Qw  + 16777216;              // K bf16 fragment-packed
  unsigned short* Vfw = Kw  + 16777216;              // V bf16 V-packed
  unsigned short* Aw  = Vfw + 16777216;              // attn out bf16 [B*T, 2048]

  const int M = 8192, K = 2048;

  cvt_f32_bf16<<<1024, 256, 0, stream>>>(x,  xb,  4194304);
  cvt_f32_bf16<<<256,  256, 0, stream>>>(wq, wqb, 1048576);
  cvt_f32_bf16<<<256,  256, 0, stream>>>(wk, wkb, 1048576);
  cvt_f32_bf16<<<256,  256, 0, stream>>>(wv, wvb, 1048576);
  cvt_f32_bf16<<<256,  256, 0, stream>>>(wo, wob, 1048576);

  // fused QKV: N = 6144, 24x32 = 768 blocks
  gemm256<0><<<dim3(768), 512, 0, stream>>>(xb, wqb, bq, bk, bv,
                                            kout, vout, Qw, Kw, Vfw,
                                            nullptr, M, 6144, K);

  attn_fwd<<<dim3(4096), 64, 0, stream>>>(Qw, Kw, Vfw, Aw);

  // out projection: N = 2048, 8x32 = 256 blocks
  gemm256<3><<<dim3(256), 512, 0, stream>>>(Aw, wob, bo, nullptr, nullptr,
                                            nullptr, nullptr, nullptr, nullptr, nullptr,
                                            out, M, 2048, K);
}